// Round 9
// baseline (2713.190 us; speedup 1.0000x reference)
//
#include <hip/hip_runtime.h>
#include <hip/hip_bf16.h>

// EdgeGNN: 3x EdgeConv(mean) + final linear.
// Algebra: h'_i = relu( [h_i | mean_j h_j] @ [Wtop - Wbot; Wbot] + b ), 0 if deg==0.
// R15: PERSISTENT MEGA-KERNEL. R10's decomposed accounting shows ~150us of the 271us is
// per-enqueue overhead (~12us x 11 ops). This collapses the chain to 2 ops: one memset
// (deg + barrier counters) + one persistent kernel with hand-rolled grid barriers:
// P0 {deg-count, W-prep, x->bf16} | scan | fill | 3x{agg | gemm} | final gemm.
// Residency guarantee (no deadlock): grid=1536=6 blk/CU, __launch_bounds__(256,6)
// (VGPR<=85 -> >=6 waves/SIMD), LDS 18432B (8/CU capable). Barriers: single-use
// counters + agent-scope acq/rel atomics + __threadfence (cross-XCD visibility).
// Phase bodies are byte-level ports of R10's kernels (R7 agg, 64x64 GEMM, parallel scan).

typedef short short8 __attribute__((ext_vector_type(8)));
typedef unsigned short ushort8v __attribute__((ext_vector_type(8)));
typedef float float4v __attribute__((ext_vector_type(4)));

static __device__ __forceinline__ float bf2f(unsigned short u) {
    union { unsigned int i; float f; } c; c.i = ((unsigned int)u) << 16; return c.f;
}
static __device__ __forceinline__ unsigned short f2bf(float f) {
    union { float f; unsigned int i; } c; c.f = f;
    unsigned int u = c.i;
    return (unsigned short)((u + 0x7FFFu + ((u >> 16) & 1u)) >> 16);  // RNE
}

#define LDK 72
#define SMEM_BYTES 18432

// grid barrier: single-use counter per phase (barr zeroed by host memset).
static __device__ __forceinline__ void gbar(int* barr, int p, int nb) {
    __syncthreads();
    if (threadIdx.x == 0) {
        __threadfence();  // release prior writes (agent scope, L2 wb)
        __hip_atomic_fetch_add(&barr[p], 1, __ATOMIC_ACQ_REL, __HIP_MEMORY_SCOPE_AGENT);
        while (__hip_atomic_load(&barr[p], __ATOMIC_ACQUIRE, __HIP_MEMORY_SCOPE_AGENT) < nb)
            __builtin_amdgcn_s_sleep(4);
        __threadfence();  // acquire side
    }
    __syncthreads();
}

// ---------------- GEMM tile body (64x64), verbatim from R10 gemm_kernel ----------------
template <int MODE, int K>
static __device__ void gemm_body(int bm, int bn,
                                 const unsigned short* __restrict__ A1,
                                 const unsigned short* __restrict__ A2,
                                 const unsigned short* __restrict__ Bt,
                                 const float* __restrict__ bias,
                                 const int* __restrict__ deg,
                                 unsigned short* __restrict__ outB,
                                 float* __restrict__ outF,
                                 int M, unsigned char* smem) {
    unsigned short* ldsA = (unsigned short*)smem;
    unsigned short* ldsB = ldsA + 64 * LDK;
    constexpr int NIT = K / 64;
    int t = threadIdx.x;
    int lane = t & 63, wave = t >> 6;
    int wm = wave >> 1, wn = wave & 1;
    int lr = lane & 15, q = lane >> 4;

    float4v acc[2][2];
#pragma unroll
    for (int i = 0; i < 2; i++)
#pragma unroll
        for (int j = 0; j < 2; j++) { float4v z = {0.f, 0.f, 0.f, 0.f}; acc[i][j] = z; }

    int r = t >> 2;
    int quarter = t & 3;
    int rowA = bm * 64 + r;
    if (rowA >= M) rowA = M - 1;  // clamp: duplicate row, stores masked below
    const unsigned short* gB0 = Bt + (long)(bn * 64 + r) * K + quarter * 16;
    unsigned short* sA = ldsA + r * LDK + quarter * 16;
    unsigned short* sB = ldsB + r * LDK + quarter * 16;

    auto addrA = [&](int kk) -> const unsigned short* {
        if (MODE == 1 || kk < 256) return A1 + (long)rowA * 1024 + kk + quarter * 16;
        return A2 + (long)rowA * 256 + (kk - 256) + quarter * 16;
    };

    const unsigned short* pa = addrA(0);
    uint4 a0 = *(const uint4*)pa;
    uint4 a1 = *(const uint4*)(pa + 8);
    uint4 b0 = *(const uint4*)gB0;
    uint4 b1 = *(const uint4*)(gB0 + 8);

    for (int it = 0; it < NIT; ++it) {
        __syncthreads();
        *(uint4*)sA = a0; *(uint4*)(sA + 8) = a1;
        *(uint4*)sB = b0; *(uint4*)(sB + 8) = b1;
        __syncthreads();
        if (it + 1 < NIT) {
            int kn = (it + 1) << 6;
            const unsigned short* pn = addrA(kn);
            a0 = *(const uint4*)pn;
            a1 = *(const uint4*)(pn + 8);
            b0 = *(const uint4*)(gB0 + kn);
            b1 = *(const uint4*)(gB0 + kn + 8);
        }
#pragma unroll
        for (int ks = 0; ks < 2; ++ks) {
            short8 af[2], bfr[2];
#pragma unroll
            for (int mi = 0; mi < 2; ++mi)
                af[mi] = *(const short8*)(ldsA + (wm * 32 + mi * 16 + lr) * LDK + ks * 32 + q * 8);
#pragma unroll
            for (int ni = 0; ni < 2; ++ni)
                bfr[ni] = *(const short8*)(ldsB + (wn * 32 + ni * 16 + lr) * LDK + ks * 32 + q * 8);
#pragma unroll
            for (int mi = 0; mi < 2; ++mi)
#pragma unroll
                for (int ni = 0; ni < 2; ++ni)
                    acc[mi][ni] = __builtin_amdgcn_mfma_f32_16x16x32_bf16(af[mi], bfr[ni], acc[mi][ni], 0, 0, 0);
        }
    }

    __syncthreads();  // all waves done reading ldsA/ldsB; reuse smem for C tile

    if (MODE == 0) {
        unsigned short* C = (unsigned short*)smem;
#pragma unroll
        for (int mi = 0; mi < 2; ++mi) {
#pragma unroll
            for (int ni = 0; ni < 2; ++ni) {
                int cn = wn * 32 + ni * 16 + lr;
                float bv = bias[bn * 64 + cn];
                int rl0 = wm * 32 + mi * 16 + q * 4;
#pragma unroll
                for (int r4 = 0; r4 < 4; ++r4) {
                    float v = fmaxf(acc[mi][ni][r4] + bv, 0.0f);
                    C[(rl0 + r4) * LDK + cn] = f2bf(v);
                }
            }
        }
        __syncthreads();
#pragma unroll
        for (int j = 0; j < 2; ++j) {
            int chunk = t + j * 256;
            int row = chunk >> 3, h = chunk & 7;
            int rg = bm * 64 + row;
            if (rg < M) {
                short8 v = *(const short8*)(C + row * LDK + h * 8);
                if (deg[rg] <= 0) { short8 z = {0, 0, 0, 0, 0, 0, 0, 0}; v = z; }
                *(short8*)(outB + (long)rg * 1024 + bn * 64 + h * 8) = v;
            }
        }
    } else {
        float* Cf = (float*)smem;
#pragma unroll
        for (int mi = 0; mi < 2; ++mi) {
#pragma unroll
            for (int ni = 0; ni < 2; ++ni) {
                int cn = wn * 32 + ni * 16 + lr;
                float bv = bias[bn * 64 + cn];
                int rl0 = wm * 32 + mi * 16 + q * 4;
#pragma unroll
                for (int r4 = 0; r4 < 4; ++r4)
                    Cf[(rl0 + r4) * 68 + cn] = acc[mi][ni][r4] + bv;
            }
        }
        __syncthreads();
#pragma unroll
        for (int j = 0; j < 4; ++j) {
            int chunk = t + j * 256;
            int row = chunk >> 4, h = chunk & 15;
            int rg = bm * 64 + row;
            if (rg < M) {
                float4 v = *(const float4*)(Cf + row * 68 + h * 4);
                *(float4*)(outF + (long)rg * 256 + bn * 64 + h * 4) = v;
            }
        }
    }
    __syncthreads();  // epilogue LDS reads done before next tile's writes
}

// ---------------- agg body: R7 two-row gather, 4 nodes per virtual block ----------------
static __device__ void agg_body(int vb, const unsigned short* __restrict__ H,
                                const int* __restrict__ offs, const int* __restrict__ esrc,
                                unsigned short* __restrict__ Hbar, int N) {
    int wave = threadIdx.x >> 6, lane = threadIdx.x & 63;
    int i = vb * 4 + wave;
    if (i >= N) return;
    int half = lane >> 5;
    int c = (lane & 31) * 8;
    float a[8];
#pragma unroll
    for (int j = 0; j < 8; ++j) a[j] = 0.f;
    int e0 = offs[i], e1 = offs[i + 1];
    int e = e0;
    for (; e + 8 <= e1; e += 8) {
        int p0 = esrc[e],     p1 = esrc[e + 1];
        int p2 = esrc[e + 2], p3 = esrc[e + 3];
        int p4 = esrc[e + 4], p5 = esrc[e + 5];
        int p6 = esrc[e + 6], p7 = esrc[e + 7];
        int s0 = half ? p1 : p0;
        int s1 = half ? p3 : p2;
        int s2 = half ? p5 : p4;
        int s3 = half ? p7 : p6;
        ushort8v r0 = *(const ushort8v*)(H + (long)s0 * 1024 + c);
        ushort8v r1 = *(const ushort8v*)(H + (long)s1 * 1024 + c);
        ushort8v r2 = *(const ushort8v*)(H + (long)s2 * 1024 + c);
        ushort8v r3 = *(const ushort8v*)(H + (long)s3 * 1024 + c);
#pragma unroll
        for (int j = 0; j < 8; ++j)
            a[j] += (bf2f(r0[j]) + bf2f(r1[j])) + (bf2f(r2[j]) + bf2f(r3[j]));
    }
    for (; e + 4 <= e1; e += 4) {
        int p0 = esrc[e],     p1 = esrc[e + 1];
        int p2 = esrc[e + 2], p3 = esrc[e + 3];
        int s0 = half ? p1 : p0;
        int s1 = half ? p3 : p2;
        ushort8v r0 = *(const ushort8v*)(H + (long)s0 * 1024 + c);
        ushort8v r1 = *(const ushort8v*)(H + (long)s1 * 1024 + c);
#pragma unroll
        for (int j = 0; j < 8; ++j)
            a[j] += bf2f(r0[j]) + bf2f(r1[j]);
    }
    for (; e < e1; e += 2) {
        int pa = esrc[e];
        int pb = (e + 1 < e1) ? esrc[e + 1] : pa;
        int s = half ? pb : pa;
        float m = (half && (e + 1 >= e1)) ? 0.f : 1.f;
        ushort8v r = *(const ushort8v*)(H + (long)s * 1024 + c);
#pragma unroll
        for (int j = 0; j < 8; ++j)
            a[j] = fmaf(bf2f(r[j]), m, a[j]);
    }
    int d = e1 - e0;
    float inv = (d > 0) ? 1.0f / (float)d : 0.0f;
    ushort8v w;
#pragma unroll
    for (int j = 0; j < 8; ++j) {
        float tsum = a[j] + __shfl_xor(a[j], 32);
        w[j] = f2bf(tsum * inv);
    }
    if (half == 0)
        *(ushort8v*)(Hbar + (long)i * 256 + c) = w;
}

// ---------------- mega kernel ----------------
__global__ __launch_bounds__(256, 6)
void mega_kernel(const float* __restrict__ x,
                 const int* __restrict__ src, const int* __restrict__ dst, int E,
                 const float* __restrict__ W0, const float* __restrict__ W1,
                 const float* __restrict__ W2, const float* __restrict__ Wf,
                 const float* __restrict__ b0p, const float* __restrict__ b1p,
                 const float* __restrict__ b2p, const float* __restrict__ bfp,
                 int* __restrict__ deg, int* __restrict__ offs, int* __restrict__ cursor,
                 int* __restrict__ esrc,
                 unsigned short* __restrict__ Wc0, unsigned short* __restrict__ Wc1,
                 unsigned short* __restrict__ Wc2, unsigned short* __restrict__ Wft,
                 unsigned short* __restrict__ Ucat, unsigned short* __restrict__ Hbar,
                 float* __restrict__ out, int* __restrict__ barr,
                 int N, int EB, int xblocks, int nbScan) {
    __shared__ __align__(16) unsigned char smem[SMEM_BYTES];
    int bid = blockIdx.x, t = threadIdx.x;
    int NB = gridDim.x;

    // ================= P0: deg count + W-prep + x->bf16 =================
    {
        float(*ta)[33] = (float(*)[33])smem;
        float(*tb)[33] = (float(*)[33])(smem + 32 * 33 * 4);
        int vbTot = EB + 448 + xblocks;
        for (int bb = bid; bb < vbTot; bb += NB) {
            if (bb < EB) {
                int idx = bb * 256 + t;
                if (idx < E) atomicAdd(&deg[dst[idx]], 1);
            } else {
                int bb2 = bb - EB;
                int r0 = t >> 5, c = t & 31;
                if (bb2 < 192) {
                    const float* W = (bb2 < 64) ? W0 : (bb2 < 128) ? W1 : W2;
                    unsigned short* Wc = (bb2 < 64) ? Wc0 : (bb2 < 128) ? Wc1 : Wc2;
                    int t64 = bb2 & 63;
                    int k0 = (t64 >> 3) * 32, n0 = (t64 & 7) * 32;
#pragma unroll
                    for (int it = 0; it < 4; ++it) {
                        int r = r0 + it * 8;
                        float a = W[(k0 + r) * 256 + n0 + c];
                        float bv = W[(k0 + r + 256) * 256 + n0 + c];
                        ta[r][c] = a - bv;
                        tb[r][c] = bv;
                    }
                    __syncthreads();
#pragma unroll
                    for (int it = 0; it < 4; ++it) {
                        int r = r0 + it * 8;
                        Wc[(n0 + r) * 512 + k0 + c] = f2bf(ta[c][r]);
                        Wc[(n0 + r) * 512 + 256 + k0 + c] = f2bf(tb[c][r]);
                    }
                    __syncthreads();  // LDS reuse across grid-stride iters
                } else if (bb2 < 448) {
                    int t256 = bb2 - 192;
                    int k0 = (t256 >> 3) * 32, n0 = (t256 & 7) * 32;
#pragma unroll
                    for (int it = 0; it < 4; ++it) {
                        int r = r0 + it * 8;
                        ta[r][c] = Wf[(k0 + r) * 256 + n0 + c];
                    }
                    __syncthreads();
#pragma unroll
                    for (int it = 0; it < 4; ++it) {
                        int r = r0 + it * 8;
                        Wft[(n0 + r) * 1024 + k0 + c] = f2bf(ta[c][r]);
                    }
                    __syncthreads();  // LDS reuse across grid-stride iters
                } else {
                    long base = (long)(bb2 - 448) * 2048 + t * 8;
                    if (base < (long)N * 256) {
                        int i = (int)(base >> 8), cc = (int)(base & 255);
                        const float4* xp = (const float4*)(x + base);
                        float4 v0 = xp[0], v1 = xp[1];
                        ushort4 w0, w1;
                        w0.x = f2bf(v0.x); w0.y = f2bf(v0.y); w0.z = f2bf(v0.z); w0.w = f2bf(v0.w);
                        w1.x = f2bf(v1.x); w1.y = f2bf(v1.y); w1.z = f2bf(v1.z); w1.w = f2bf(v1.w);
                        unsigned short* up = Ucat + (long)i * 1024 + cc;
                        *(ushort4*)up = w0;
                        *(ushort4*)(up + 4) = w1;
                    }
                }
            }
        }
    }
    gbar(barr, 0, NB);

    // ================= P1: CSR scan (redundant-prefix), blocks [0,nbScan) =================
    if (bid < nbScan) {
        int* part = (int*)smem;          // [256]
        int* pre = (int*)smem + 256;     // [128]
        int b = bid;
        int beg = b * 128;
        int end = beg + 128; if (end > N) end = N;
        int s = 0;
        for (int i = t; i < beg; i += 256) s += deg[i];
        part[t] = s;
        __syncthreads();
#pragma unroll
        for (int off = 128; off > 0; off >>= 1) {
            if (t < off) part[t] += part[t + off];
            __syncthreads();
        }
        int base = part[0];
        int cnt = end - beg;
        if (t < 128) pre[t] = (t < cnt) ? deg[beg + t] : 0;
        __syncthreads();
        for (int off = 1; off < 128; off <<= 1) {
            int v = 0;
            if (t < 128 && t >= off) v = pre[t - off];
            __syncthreads();
            if (t < 128 && t >= off) pre[t] += v;
            __syncthreads();
        }
        if (t < cnt) {
            int excl = base + (t ? pre[t - 1] : 0);
            offs[beg + t] = excl;
            cursor[beg + t] = excl;
        }
        if (end == N && t == 0) offs[N] = base + (cnt ? pre[cnt - 1] : 0);
    }
    gbar(barr, 1, NB);

    // ================= P2: bucket fill =================
    for (int idx = bid * 256 + t; idx < E; idx += NB * 256) {
        int p = atomicAdd(&cursor[dst[idx]], 1);
        esrc[p] = src[idx];
    }
    gbar(barr, 2, NB);

    // ================= layers =================
    int gm = (N + 63) / 64;
    int ab = (N + 3) / 4;
    int tiles = gm * 4;
#pragma unroll 1
    for (int l = 0; l < 3; ++l) {
        const unsigned short* A1 = Ucat + l * 256;
        const unsigned short* Wc = (l == 0) ? Wc0 : (l == 1) ? Wc1 : Wc2;
        const float* bias = (l == 0) ? b0p : (l == 1) ? b1p : b2p;
        unsigned short* outB = Ucat + (l + 1) * 256;

        for (int vb = bid; vb < ab; vb += NB)
            agg_body(vb, A1, offs, esrc, Hbar, N);
        gbar(barr, 3 + 2 * l, NB);

        for (int vb = bid; vb < tiles; vb += NB) {
            int bm = vb % gm, bn = vb / gm;
            gemm_body<0, 512>(bm, bn, A1, Hbar, Wc, bias, deg, outB, nullptr, N, smem);
        }
        gbar(barr, 4 + 2 * l, NB);
    }

    // ================= final linear =================
    for (int vb = bid; vb < tiles; vb += NB) {
        int bm = vb % gm, bn = vb / gm;
        gemm_body<1, 1024>(bm, bn, Ucat, nullptr, Wft, bfp, nullptr, nullptr, out, N, smem);
    }
}

extern "C" void kernel_launch(void* const* d_in, const int* in_sizes, int n_in,
                              void* d_out, int out_size, void* d_ws, size_t ws_size,
                              hipStream_t stream) {
    const float* x = (const float*)d_in[0];
    const int* ei = (const int*)d_in[1];
    const float* W[3] = {(const float*)d_in[2], (const float*)d_in[4], (const float*)d_in[6]};
    const float* b[3] = {(const float*)d_in[3], (const float*)d_in[5], (const float*)d_in[7]};
    const float* Wfp = (const float*)d_in[8];
    const float* bfp = (const float*)d_in[9];

    int N = in_sizes[0] / 256;
    int E = in_sizes[1] / 2;
    const int* src = ei;
    const int* dst = ei + E;

    char* p = (char*)d_ws;
    auto alloc = [&](size_t bytes) { char* r = p; p += (bytes + 255) & ~(size_t)255; return r; };
    int* deg = (int*)alloc((size_t)N * 4 + 64);   // barr rides in the same zeroed region
    int* barr = deg + N;                          // 16 ints
    int* offs = (int*)alloc((size_t)(N + 1) * 4);
    int* cursor = (int*)alloc((size_t)N * 4);
    int* esrc = (int*)alloc((size_t)E * 4);
    unsigned short* Wc[3];
    for (int l = 0; l < 3; l++) Wc[l] = (unsigned short*)alloc(256 * 512 * 2);
    unsigned short* Wft = (unsigned short*)alloc(256 * 1024 * 2);
    unsigned short* Ucat = (unsigned short*)alloc((size_t)N * 1024 * 2);
    unsigned short* Hbar = (unsigned short*)alloc((size_t)N * 256 * 2);

    hipMemsetAsync(deg, 0, (size_t)N * 4 + 64, stream);  // zero deg + barrier counters

    int EB = (E + 255) / 256;
    int xblocks = (N * 256 + 2047) / 2048;
    int nbScan = (N + 127) / 128;
    int NB = 1536;  // 6 blocks/CU: guaranteed co-resident under launch_bounds(256,6)+18KB LDS

    mega_kernel<<<NB, 256, 0, stream>>>(x, src, dst, E,
                                        W[0], W[1], W[2], Wfp,
                                        b[0], b[1], b[2], bfp,
                                        deg, offs, cursor, esrc,
                                        Wc[0], Wc[1], Wc[2], Wft,
                                        Ucat, Hbar, (float*)d_out, barr,
                                        N, EB, xblocks, nbScan);
}

// Round 10
// 1874.986 us; speedup vs baseline: 1.4470x; 1.4470x over previous
//
#include <hip/hip_runtime.h>
#include <hip/hip_bf16.h>

// EdgeGNN: 3x EdgeConv(mean) + final linear.
// Algebra: h'_i = relu( [h_i | mean_j h_j] @ [Wtop - Wbot; Wbot] + b ), 0 if deg==0.
// R16: R15 mega-kernel with the grid-barrier FIXED. R15's 2.7ms post-mortem: polling with
// agent-scope ACQUIRE loads emits a cache-invalidate per poll iteration -> 1536 spinning
// blocks continuously wiped every XCD's L2 (workers crawl, phases start cold; VALU 1.2%,
// HBM 2.5%). Fix: poll via RELAXED atomic fetch_add(0) (RMW at coherence point, NO cache
// side effects) + s_sleep(64) backoff; exactly one release fence (wbL2) before arrival
// and one acquire fence (inv) after exit. Phase bodies unchanged (R10's proven kernels).

typedef short short8 __attribute__((ext_vector_type(8)));
typedef unsigned short ushort8v __attribute__((ext_vector_type(8)));
typedef float float4v __attribute__((ext_vector_type(4)));

static __device__ __forceinline__ float bf2f(unsigned short u) {
    union { unsigned int i; float f; } c; c.i = ((unsigned int)u) << 16; return c.f;
}
static __device__ __forceinline__ unsigned short f2bf(float f) {
    union { float f; unsigned int i; } c; c.f = f;
    unsigned int u = c.i;
    return (unsigned short)((u + 0x7FFFu + ((u >> 16) & 1u)) >> 16);  // RNE
}

#define LDK 72
#define SMEM_BYTES 18432

// grid barrier: single-use counter per phase (barr zeroed by host memset).
// Poll = relaxed RMW (no invalidate). One release fence before arrival, one acquire after.
static __device__ __forceinline__ void gbar(int* barr, int p, int nb) {
    __syncthreads();
    if (threadIdx.x == 0) {
        __threadfence();  // release: write back this XCD's L2 (publishes block's stores)
        __hip_atomic_fetch_add(&barr[p], 1, __ATOMIC_RELAXED, __HIP_MEMORY_SCOPE_AGENT);
        while (__hip_atomic_fetch_add(&barr[p], 0, __ATOMIC_RELAXED,
                                      __HIP_MEMORY_SCOPE_AGENT) < nb)
            __builtin_amdgcn_s_sleep(64);   // ~4096 cycles between polls, no cache traffic
        __threadfence();  // acquire: invalidate once, see other XCDs' published stores
    }
    __syncthreads();
}

// ---------------- GEMM tile body (64x64), verbatim from R10 gemm_kernel ----------------
template <int MODE, int K>
static __device__ void gemm_body(int bm, int bn,
                                 const unsigned short* __restrict__ A1,
                                 const unsigned short* __restrict__ A2,
                                 const unsigned short* __restrict__ Bt,
                                 const float* __restrict__ bias,
                                 const int* __restrict__ deg,
                                 unsigned short* __restrict__ outB,
                                 float* __restrict__ outF,
                                 int M, unsigned char* smem) {
    unsigned short* ldsA = (unsigned short*)smem;
    unsigned short* ldsB = ldsA + 64 * LDK;
    constexpr int NIT = K / 64;
    int t = threadIdx.x;
    int lane = t & 63, wave = t >> 6;
    int wm = wave >> 1, wn = wave & 1;
    int lr = lane & 15, q = lane >> 4;

    float4v acc[2][2];
#pragma unroll
    for (int i = 0; i < 2; i++)
#pragma unroll
        for (int j = 0; j < 2; j++) { float4v z = {0.f, 0.f, 0.f, 0.f}; acc[i][j] = z; }

    int r = t >> 2;
    int quarter = t & 3;
    int rowA = bm * 64 + r;
    if (rowA >= M) rowA = M - 1;  // clamp: duplicate row, stores masked below
    const unsigned short* gB0 = Bt + (long)(bn * 64 + r) * K + quarter * 16;
    unsigned short* sA = ldsA + r * LDK + quarter * 16;
    unsigned short* sB = ldsB + r * LDK + quarter * 16;

    auto addrA = [&](int kk) -> const unsigned short* {
        if (MODE == 1 || kk < 256) return A1 + (long)rowA * 1024 + kk + quarter * 16;
        return A2 + (long)rowA * 256 + (kk - 256) + quarter * 16;
    };

    const unsigned short* pa = addrA(0);
    uint4 a0 = *(const uint4*)pa;
    uint4 a1 = *(const uint4*)(pa + 8);
    uint4 b0 = *(const uint4*)gB0;
    uint4 b1 = *(const uint4*)(gB0 + 8);

    for (int it = 0; it < NIT; ++it) {
        __syncthreads();
        *(uint4*)sA = a0; *(uint4*)(sA + 8) = a1;
        *(uint4*)sB = b0; *(uint4*)(sB + 8) = b1;
        __syncthreads();
        if (it + 1 < NIT) {
            int kn = (it + 1) << 6;
            const unsigned short* pn = addrA(kn);
            a0 = *(const uint4*)pn;
            a1 = *(const uint4*)(pn + 8);
            b0 = *(const uint4*)(gB0 + kn);
            b1 = *(const uint4*)(gB0 + kn + 8);
        }
#pragma unroll
        for (int ks = 0; ks < 2; ++ks) {
            short8 af[2], bfr[2];
#pragma unroll
            for (int mi = 0; mi < 2; ++mi)
                af[mi] = *(const short8*)(ldsA + (wm * 32 + mi * 16 + lr) * LDK + ks * 32 + q * 8);
#pragma unroll
            for (int ni = 0; ni < 2; ++ni)
                bfr[ni] = *(const short8*)(ldsB + (wn * 32 + ni * 16 + lr) * LDK + ks * 32 + q * 8);
#pragma unroll
            for (int mi = 0; mi < 2; ++mi)
#pragma unroll
                for (int ni = 0; ni < 2; ++ni)
                    acc[mi][ni] = __builtin_amdgcn_mfma_f32_16x16x32_bf16(af[mi], bfr[ni], acc[mi][ni], 0, 0, 0);
        }
    }

    __syncthreads();  // all waves done reading ldsA/ldsB; reuse smem for C tile

    if (MODE == 0) {
        unsigned short* C = (unsigned short*)smem;
#pragma unroll
        for (int mi = 0; mi < 2; ++mi) {
#pragma unroll
            for (int ni = 0; ni < 2; ++ni) {
                int cn = wn * 32 + ni * 16 + lr;
                float bv = bias[bn * 64 + cn];
                int rl0 = wm * 32 + mi * 16 + q * 4;
#pragma unroll
                for (int r4 = 0; r4 < 4; ++r4) {
                    float v = fmaxf(acc[mi][ni][r4] + bv, 0.0f);
                    C[(rl0 + r4) * LDK + cn] = f2bf(v);
                }
            }
        }
        __syncthreads();
#pragma unroll
        for (int j = 0; j < 2; ++j) {
            int chunk = t + j * 256;
            int row = chunk >> 3, h = chunk & 7;
            int rg = bm * 64 + row;
            if (rg < M) {
                short8 v = *(const short8*)(C + row * LDK + h * 8);
                if (deg[rg] <= 0) { short8 z = {0, 0, 0, 0, 0, 0, 0, 0}; v = z; }
                *(short8*)(outB + (long)rg * 1024 + bn * 64 + h * 8) = v;
            }
        }
    } else {
        float* Cf = (float*)smem;
#pragma unroll
        for (int mi = 0; mi < 2; ++mi) {
#pragma unroll
            for (int ni = 0; ni < 2; ++ni) {
                int cn = wn * 32 + ni * 16 + lr;
                float bv = bias[bn * 64 + cn];
                int rl0 = wm * 32 + mi * 16 + q * 4;
#pragma unroll
                for (int r4 = 0; r4 < 4; ++r4)
                    Cf[(rl0 + r4) * 68 + cn] = acc[mi][ni][r4] + bv;
            }
        }
        __syncthreads();
#pragma unroll
        for (int j = 0; j < 4; ++j) {
            int chunk = t + j * 256;
            int row = chunk >> 4, h = chunk & 15;
            int rg = bm * 64 + row;
            if (rg < M) {
                float4 v = *(const float4*)(Cf + row * 68 + h * 4);
                *(float4*)(outF + (long)rg * 256 + bn * 64 + h * 4) = v;
            }
        }
    }
    __syncthreads();  // epilogue LDS reads done before next tile's writes
}

// ---------------- agg body: R7 two-row gather, 4 nodes per virtual block ----------------
static __device__ void agg_body(int vb, const unsigned short* __restrict__ H,
                                const int* __restrict__ offs, const int* __restrict__ esrc,
                                unsigned short* __restrict__ Hbar, int N) {
    int wave = threadIdx.x >> 6, lane = threadIdx.x & 63;
    int i = vb * 4 + wave;
    if (i >= N) return;
    int half = lane >> 5;
    int c = (lane & 31) * 8;
    float a[8];
#pragma unroll
    for (int j = 0; j < 8; ++j) a[j] = 0.f;
    int e0 = offs[i], e1 = offs[i + 1];
    int e = e0;
    for (; e + 8 <= e1; e += 8) {
        int p0 = esrc[e],     p1 = esrc[e + 1];
        int p2 = esrc[e + 2], p3 = esrc[e + 3];
        int p4 = esrc[e + 4], p5 = esrc[e + 5];
        int p6 = esrc[e + 6], p7 = esrc[e + 7];
        int s0 = half ? p1 : p0;
        int s1 = half ? p3 : p2;
        int s2 = half ? p5 : p4;
        int s3 = half ? p7 : p6;
        ushort8v r0 = *(const ushort8v*)(H + (long)s0 * 1024 + c);
        ushort8v r1 = *(const ushort8v*)(H + (long)s1 * 1024 + c);
        ushort8v r2 = *(const ushort8v*)(H + (long)s2 * 1024 + c);
        ushort8v r3 = *(const ushort8v*)(H + (long)s3 * 1024 + c);
#pragma unroll
        for (int j = 0; j < 8; ++j)
            a[j] += (bf2f(r0[j]) + bf2f(r1[j])) + (bf2f(r2[j]) + bf2f(r3[j]));
    }
    for (; e + 4 <= e1; e += 4) {
        int p0 = esrc[e],     p1 = esrc[e + 1];
        int p2 = esrc[e + 2], p3 = esrc[e + 3];
        int s0 = half ? p1 : p0;
        int s1 = half ? p3 : p2;
        ushort8v r0 = *(const ushort8v*)(H + (long)s0 * 1024 + c);
        ushort8v r1 = *(const ushort8v*)(H + (long)s1 * 1024 + c);
#pragma unroll
        for (int j = 0; j < 8; ++j)
            a[j] += bf2f(r0[j]) + bf2f(r1[j]);
    }
    for (; e < e1; e += 2) {
        int pa = esrc[e];
        int pb = (e + 1 < e1) ? esrc[e + 1] : pa;
        int s = half ? pb : pa;
        float m = (half && (e + 1 >= e1)) ? 0.f : 1.f;
        ushort8v r = *(const ushort8v*)(H + (long)s * 1024 + c);
#pragma unroll
        for (int j = 0; j < 8; ++j)
            a[j] = fmaf(bf2f(r[j]), m, a[j]);
    }
    int d = e1 - e0;
    float inv = (d > 0) ? 1.0f / (float)d : 0.0f;
    ushort8v w;
#pragma unroll
    for (int j = 0; j < 8; ++j) {
        float tsum = a[j] + __shfl_xor(a[j], 32);
        w[j] = f2bf(tsum * inv);
    }
    if (half == 0)
        *(ushort8v*)(Hbar + (long)i * 256 + c) = w;
}

// ---------------- mega kernel ----------------
__global__ __launch_bounds__(256, 6)
void mega_kernel(const float* __restrict__ x,
                 const int* __restrict__ src, const int* __restrict__ dst, int E,
                 const float* __restrict__ W0, const float* __restrict__ W1,
                 const float* __restrict__ W2, const float* __restrict__ Wf,
                 const float* __restrict__ b0p, const float* __restrict__ b1p,
                 const float* __restrict__ b2p, const float* __restrict__ bfp,
                 int* __restrict__ deg, int* __restrict__ offs, int* __restrict__ cursor,
                 int* __restrict__ esrc,
                 unsigned short* __restrict__ Wc0, unsigned short* __restrict__ Wc1,
                 unsigned short* __restrict__ Wc2, unsigned short* __restrict__ Wft,
                 unsigned short* __restrict__ Ucat, unsigned short* __restrict__ Hbar,
                 float* __restrict__ out, int* __restrict__ barr,
                 int N, int EB, int xblocks, int nbScan) {
    __shared__ __align__(16) unsigned char smem[SMEM_BYTES];
    int bid = blockIdx.x, t = threadIdx.x;
    int NB = gridDim.x;

    // ================= P0: deg count + W-prep + x->bf16 =================
    {
        float(*ta)[33] = (float(*)[33])smem;
        float(*tb)[33] = (float(*)[33])(smem + 32 * 33 * 4);
        int vbTot = EB + 448 + xblocks;
        for (int bb = bid; bb < vbTot; bb += NB) {
            if (bb < EB) {
                int idx = bb * 256 + t;
                if (idx < E) atomicAdd(&deg[dst[idx]], 1);
            } else {
                int bb2 = bb - EB;
                int r0 = t >> 5, c = t & 31;
                if (bb2 < 192) {
                    const float* W = (bb2 < 64) ? W0 : (bb2 < 128) ? W1 : W2;
                    unsigned short* Wc = (bb2 < 64) ? Wc0 : (bb2 < 128) ? Wc1 : Wc2;
                    int t64 = bb2 & 63;
                    int k0 = (t64 >> 3) * 32, n0 = (t64 & 7) * 32;
#pragma unroll
                    for (int it = 0; it < 4; ++it) {
                        int r = r0 + it * 8;
                        float a = W[(k0 + r) * 256 + n0 + c];
                        float bv = W[(k0 + r + 256) * 256 + n0 + c];
                        ta[r][c] = a - bv;
                        tb[r][c] = bv;
                    }
                    __syncthreads();
#pragma unroll
                    for (int it = 0; it < 4; ++it) {
                        int r = r0 + it * 8;
                        Wc[(n0 + r) * 512 + k0 + c] = f2bf(ta[c][r]);
                        Wc[(n0 + r) * 512 + 256 + k0 + c] = f2bf(tb[c][r]);
                    }
                    __syncthreads();  // LDS reuse across grid-stride iters
                } else if (bb2 < 448) {
                    int t256 = bb2 - 192;
                    int k0 = (t256 >> 3) * 32, n0 = (t256 & 7) * 32;
#pragma unroll
                    for (int it = 0; it < 4; ++it) {
                        int r = r0 + it * 8;
                        ta[r][c] = Wf[(k0 + r) * 256 + n0 + c];
                    }
                    __syncthreads();
#pragma unroll
                    for (int it = 0; it < 4; ++it) {
                        int r = r0 + it * 8;
                        Wft[(n0 + r) * 1024 + k0 + c] = f2bf(ta[c][r]);
                    }
                    __syncthreads();  // LDS reuse across grid-stride iters
                } else {
                    long base = (long)(bb2 - 448) * 2048 + t * 8;
                    if (base < (long)N * 256) {
                        int i = (int)(base >> 8), cc = (int)(base & 255);
                        const float4* xp = (const float4*)(x + base);
                        float4 v0 = xp[0], v1 = xp[1];
                        ushort4 w0, w1;
                        w0.x = f2bf(v0.x); w0.y = f2bf(v0.y); w0.z = f2bf(v0.z); w0.w = f2bf(v0.w);
                        w1.x = f2bf(v1.x); w1.y = f2bf(v1.y); w1.z = f2bf(v1.z); w1.w = f2bf(v1.w);
                        unsigned short* up = Ucat + (long)i * 1024 + cc;
                        *(ushort4*)up = w0;
                        *(ushort4*)(up + 4) = w1;
                    }
                }
            }
        }
    }
    gbar(barr, 0, NB);

    // ================= P1: CSR scan (redundant-prefix), blocks [0,nbScan) =================
    if (bid < nbScan) {
        int* part = (int*)smem;          // [256]
        int* pre = (int*)smem + 256;     // [128]
        int b = bid;
        int beg = b * 128;
        int end = beg + 128; if (end > N) end = N;
        int s = 0;
        for (int i = t; i < beg; i += 256) s += deg[i];
        part[t] = s;
        __syncthreads();
#pragma unroll
        for (int off = 128; off > 0; off >>= 1) {
            if (t < off) part[t] += part[t + off];
            __syncthreads();
        }
        int base = part[0];
        int cnt = end - beg;
        if (t < 128) pre[t] = (t < cnt) ? deg[beg + t] : 0;
        __syncthreads();
        for (int off = 1; off < 128; off <<= 1) {
            int v = 0;
            if (t < 128 && t >= off) v = pre[t - off];
            __syncthreads();
            if (t < 128 && t >= off) pre[t] += v;
            __syncthreads();
        }
        if (t < cnt) {
            int excl = base + (t ? pre[t - 1] : 0);
            offs[beg + t] = excl;
            cursor[beg + t] = excl;
        }
        if (end == N && t == 0) offs[N] = base + (cnt ? pre[cnt - 1] : 0);
    }
    gbar(barr, 1, NB);

    // ================= P2: bucket fill =================
    for (int idx = bid * 256 + t; idx < E; idx += NB * 256) {
        int p = atomicAdd(&cursor[dst[idx]], 1);
        esrc[p] = src[idx];
    }
    gbar(barr, 2, NB);

    // ================= layers =================
    int gm = (N + 63) / 64;
    int ab = (N + 3) / 4;
    int tiles = gm * 4;
#pragma unroll 1
    for (int l = 0; l < 3; ++l) {
        const unsigned short* A1 = Ucat + l * 256;
        const unsigned short* Wc = (l == 0) ? Wc0 : (l == 1) ? Wc1 : Wc2;
        const float* bias = (l == 0) ? b0p : (l == 1) ? b1p : b2p;
        unsigned short* outB = Ucat + (l + 1) * 256;

        for (int vb = bid; vb < ab; vb += NB)
            agg_body(vb, A1, offs, esrc, Hbar, N);
        gbar(barr, 3 + 2 * l, NB);

        for (int vb = bid; vb < tiles; vb += NB) {
            int bm = vb % gm, bn = vb / gm;
            gemm_body<0, 512>(bm, bn, A1, Hbar, Wc, bias, deg, outB, nullptr, N, smem);
        }
        gbar(barr, 4 + 2 * l, NB);
    }

    // ================= final linear =================
    for (int vb = bid; vb < tiles; vb += NB) {
        int bm = vb % gm, bn = vb / gm;
        gemm_body<1, 1024>(bm, bn, Ucat, nullptr, Wft, bfp, nullptr, nullptr, out, N, smem);
    }
}

extern "C" void kernel_launch(void* const* d_in, const int* in_sizes, int n_in,
                              void* d_out, int out_size, void* d_ws, size_t ws_size,
                              hipStream_t stream) {
    const float* x = (const float*)d_in[0];
    const int* ei = (const int*)d_in[1];
    const float* W[3] = {(const float*)d_in[2], (const float*)d_in[4], (const float*)d_in[6]};
    const float* b[3] = {(const float*)d_in[3], (const float*)d_in[5], (const float*)d_in[7]};
    const float* Wfp = (const float*)d_in[8];
    const float* bfp = (const float*)d_in[9];

    int N = in_sizes[0] / 256;
    int E = in_sizes[1] / 2;
    const int* src = ei;
    const int* dst = ei + E;

    char* p = (char*)d_ws;
    auto alloc = [&](size_t bytes) { char* r = p; p += (bytes + 255) & ~(size_t)255; return r; };
    int* deg = (int*)alloc((size_t)N * 4 + 64);   // barr rides in the same zeroed region
    int* barr = deg + N;                          // 16 ints
    int* offs = (int*)alloc((size_t)(N + 1) * 4);
    int* cursor = (int*)alloc((size_t)N * 4);
    int* esrc = (int*)alloc((size_t)E * 4);
    unsigned short* Wc[3];
    for (int l = 0; l < 3; l++) Wc[l] = (unsigned short*)alloc(256 * 512 * 2);
    unsigned short* Wft = (unsigned short*)alloc(256 * 1024 * 2);
    unsigned short* Ucat = (unsigned short*)alloc((size_t)N * 1024 * 2);
    unsigned short* Hbar = (unsigned short*)alloc((size_t)N * 256 * 2);

    hipMemsetAsync(deg, 0, (size_t)N * 4 + 64, stream);  // zero deg + barrier counters

    int EB = (E + 255) / 256;
    int xblocks = (N * 256 + 2047) / 2048;
    int nbScan = (N + 127) / 128;
    int NB = 1536;  // 6 blocks/CU: guaranteed co-resident under launch_bounds(256,6)+18KB LDS

    mega_kernel<<<NB, 256, 0, stream>>>(x, src, dst, E,
                                        W[0], W[1], W[2], Wfp,
                                        b[0], b[1], b[2], bfp,
                                        deg, offs, cursor, esrc,
                                        Wc[0], Wc[1], Wc[2], Wft,
                                        Ucat, Hbar, (float*)d_out, barr,
                                        N, EB, xblocks, nbScan);
}

// Round 11
// 468.976 us; speedup vs baseline: 5.7853x; 3.9980x over previous
//
#include <hip/hip_runtime.h>
#include <hip/hip_bf16.h>

// EdgeGNN: 3x EdgeConv(mean) + final linear.
// Algebra: h'_i = relu( [h_i | mean_j h_j] @ [Wtop - Wbot; Wbot] + b ), 0 if deg==0.
// R17: mega-kernel with PER-XCD-LEADER barrier fences. R16 post-mortem: every block did
// agent-scope wb+inv (cache-wide L2 ops) at every barrier -> 27k L2 maintenance ops
// ~= the whole 1.8ms. Fix: one leader per XCD (s_getreg XCC_ID, election RMW) does
// wbL2 after all arrivals + invL2 after all XCDs flushed; non-leaders poll a per-XCD
// V flag (relaxed RMW, no cache ops). NXCD counted at kernel start (robust placement).
// L1 staleness (leader inv doesn't touch other CUs' L1s) closed STRUCTURALLY:
// triple-buffered Hbar (only buffer with write->read->rewrite); all other buffers are
// write-once-then-read-only. Phase bodies unchanged (R10's proven kernels).

typedef short short8 __attribute__((ext_vector_type(8)));
typedef unsigned short ushort8v __attribute__((ext_vector_type(8)));
typedef float float4v __attribute__((ext_vector_type(4)));

static __device__ __forceinline__ float bf2f(unsigned short u) {
    union { unsigned int i; float f; } c; c.i = ((unsigned int)u) << 16; return c.f;
}
static __device__ __forceinline__ unsigned short f2bf(float f) {
    union { float f; unsigned int i; } c; c.f = f;
    unsigned int u = c.i;
    return (unsigned short)((u + 0x7FFFu + ((u >> 16) & 1u)) >> 16);  // RNE
}

#define LDK 72
#define SMEM_BYTES 18432
#define BARR_STRIDE 256

static __device__ __forceinline__ int get_xcd() {
    int v;
    asm volatile("s_getreg_b32 %0, hwreg(HW_REG_XCC_ID)" : "=s"(v));
    return v & 7;
}

// Grid barrier, single-use counters per phase (zeroed by host memset).
// Layout per barrier p at barr+256+p*256 (ints): [0]=arrivals, [16]=W (XCDs flushed),
// [32+x]=leader election, [64+16x]=V flag per XCD. barr[16x]=start election, [128]=NXCD.
static __device__ __forceinline__ void gbar(int* barr, int p, int nb, int xcd, int* nxcd) {
    __syncthreads();  // s_waitcnt vmcnt(0) lgkmcnt(0) + s_barrier: block's stores are in L2
    if (threadIdx.x == 0) {
        int* base = barr + 256 + p * BARR_STRIDE;
        __hip_atomic_fetch_add(base + 0, 1, __ATOMIC_RELAXED, __HIP_MEMORY_SCOPE_AGENT);
        int lead = __hip_atomic_fetch_add(base + 32 + xcd, 1, __ATOMIC_RELAXED,
                                          __HIP_MEMORY_SCOPE_AGENT);
        if (lead == 0) {
            while (__hip_atomic_fetch_add(base + 0, 0, __ATOMIC_RELAXED,
                                          __HIP_MEMORY_SCOPE_AGENT) < nb)
                __builtin_amdgcn_s_sleep(8);
            __builtin_amdgcn_fence(__ATOMIC_RELEASE, "agent");   // buffer_wbl2: publish XCD L2
            asm volatile("s_waitcnt vmcnt(0)" ::: "memory");     // wb complete
            __hip_atomic_fetch_add(base + 16, 1, __ATOMIC_RELAXED, __HIP_MEMORY_SCOPE_AGENT);
            int nx = __hip_atomic_fetch_add(nxcd, 0, __ATOMIC_RELAXED,
                                            __HIP_MEMORY_SCOPE_AGENT);
            while (__hip_atomic_fetch_add(base + 16, 0, __ATOMIC_RELAXED,
                                          __HIP_MEMORY_SCOPE_AGENT) < nx)
                __builtin_amdgcn_s_sleep(8);
            __builtin_amdgcn_fence(__ATOMIC_ACQUIRE, "agent");   // buffer_inv: drop stale L2
            asm volatile("s_waitcnt vmcnt(0)" ::: "memory");     // inv complete
            __hip_atomic_fetch_add(base + 64 + xcd * 16, 1, __ATOMIC_RELAXED,
                                   __HIP_MEMORY_SCOPE_AGENT);
        } else {
            while (__hip_atomic_fetch_add(base + 64 + xcd * 16, 0, __ATOMIC_RELAXED,
                                          __HIP_MEMORY_SCOPE_AGENT) < 1)
                __builtin_amdgcn_s_sleep(32);
        }
    }
    __syncthreads();
    asm volatile("" ::: "memory");  // no load hoisting above the barrier
}

// ---------------- GEMM tile body (64x64), verbatim from R10 gemm_kernel ----------------
template <int MODE, int K>
static __device__ void gemm_body(int bm, int bn,
                                 const unsigned short* __restrict__ A1,
                                 const unsigned short* __restrict__ A2,
                                 const unsigned short* __restrict__ Bt,
                                 const float* __restrict__ bias,
                                 const int* __restrict__ deg,
                                 unsigned short* __restrict__ outB,
                                 float* __restrict__ outF,
                                 int M, unsigned char* smem) {
    unsigned short* ldsA = (unsigned short*)smem;
    unsigned short* ldsB = ldsA + 64 * LDK;
    constexpr int NIT = K / 64;
    int t = threadIdx.x;
    int lane = t & 63, wave = t >> 6;
    int wm = wave >> 1, wn = wave & 1;
    int lr = lane & 15, q = lane >> 4;

    float4v acc[2][2];
#pragma unroll
    for (int i = 0; i < 2; i++)
#pragma unroll
        for (int j = 0; j < 2; j++) { float4v z = {0.f, 0.f, 0.f, 0.f}; acc[i][j] = z; }

    int r = t >> 2;
    int quarter = t & 3;
    int rowA = bm * 64 + r;
    if (rowA >= M) rowA = M - 1;  // clamp: duplicate row, stores masked below
    const unsigned short* gB0 = Bt + (long)(bn * 64 + r) * K + quarter * 16;
    unsigned short* sA = ldsA + r * LDK + quarter * 16;
    unsigned short* sB = ldsB + r * LDK + quarter * 16;

    auto addrA = [&](int kk) -> const unsigned short* {
        if (MODE == 1 || kk < 256) return A1 + (long)rowA * 1024 + kk + quarter * 16;
        return A2 + (long)rowA * 256 + (kk - 256) + quarter * 16;
    };

    const unsigned short* pa = addrA(0);
    uint4 a0 = *(const uint4*)pa;
    uint4 a1 = *(const uint4*)(pa + 8);
    uint4 b0 = *(const uint4*)gB0;
    uint4 b1 = *(const uint4*)(gB0 + 8);

    for (int it = 0; it < NIT; ++it) {
        __syncthreads();
        *(uint4*)sA = a0; *(uint4*)(sA + 8) = a1;
        *(uint4*)sB = b0; *(uint4*)(sB + 8) = b1;
        __syncthreads();
        if (it + 1 < NIT) {
            int kn = (it + 1) << 6;
            const unsigned short* pn = addrA(kn);
            a0 = *(const uint4*)pn;
            a1 = *(const uint4*)(pn + 8);
            b0 = *(const uint4*)(gB0 + kn);
            b1 = *(const uint4*)(gB0 + kn + 8);
        }
#pragma unroll
        for (int ks = 0; ks < 2; ++ks) {
            short8 af[2], bfr[2];
#pragma unroll
            for (int mi = 0; mi < 2; ++mi)
                af[mi] = *(const short8*)(ldsA + (wm * 32 + mi * 16 + lr) * LDK + ks * 32 + q * 8);
#pragma unroll
            for (int ni = 0; ni < 2; ++ni)
                bfr[ni] = *(const short8*)(ldsB + (wn * 32 + ni * 16 + lr) * LDK + ks * 32 + q * 8);
#pragma unroll
            for (int mi = 0; mi < 2; ++mi)
#pragma unroll
                for (int ni = 0; ni < 2; ++ni)
                    acc[mi][ni] = __builtin_amdgcn_mfma_f32_16x16x32_bf16(af[mi], bfr[ni], acc[mi][ni], 0, 0, 0);
        }
    }

    __syncthreads();  // all waves done reading ldsA/ldsB; reuse smem for C tile

    if (MODE == 0) {
        unsigned short* C = (unsigned short*)smem;
#pragma unroll
        for (int mi = 0; mi < 2; ++mi) {
#pragma unroll
            for (int ni = 0; ni < 2; ++ni) {
                int cn = wn * 32 + ni * 16 + lr;
                float bv = bias[bn * 64 + cn];
                int rl0 = wm * 32 + mi * 16 + q * 4;
#pragma unroll
                for (int r4 = 0; r4 < 4; ++r4) {
                    float v = fmaxf(acc[mi][ni][r4] + bv, 0.0f);
                    C[(rl0 + r4) * LDK + cn] = f2bf(v);
                }
            }
        }
        __syncthreads();
#pragma unroll
        for (int j = 0; j < 2; ++j) {
            int chunk = t + j * 256;
            int row = chunk >> 3, h = chunk & 7;
            int rg = bm * 64 + row;
            if (rg < M) {
                short8 v = *(const short8*)(C + row * LDK + h * 8);
                if (deg[rg] <= 0) { short8 z = {0, 0, 0, 0, 0, 0, 0, 0}; v = z; }
                *(short8*)(outB + (long)rg * 1024 + bn * 64 + h * 8) = v;
            }
        }
    } else {
        float* Cf = (float*)smem;
#pragma unroll
        for (int mi = 0; mi < 2; ++mi) {
#pragma unroll
            for (int ni = 0; ni < 2; ++ni) {
                int cn = wn * 32 + ni * 16 + lr;
                float bv = bias[bn * 64 + cn];
                int rl0 = wm * 32 + mi * 16 + q * 4;
#pragma unroll
                for (int r4 = 0; r4 < 4; ++r4)
                    Cf[(rl0 + r4) * 68 + cn] = acc[mi][ni][r4] + bv;
            }
        }
        __syncthreads();
#pragma unroll
        for (int j = 0; j < 4; ++j) {
            int chunk = t + j * 256;
            int row = chunk >> 4, h = chunk & 15;
            int rg = bm * 64 + row;
            if (rg < M) {
                float4 v = *(const float4*)(Cf + row * 68 + h * 4);
                *(float4*)(outF + (long)rg * 256 + bn * 64 + h * 4) = v;
            }
        }
    }
    __syncthreads();  // epilogue LDS reads done before next tile's writes
}

// ---------------- agg body: R7 two-row gather, 4 nodes per virtual block ----------------
static __device__ void agg_body(int vb, const unsigned short* __restrict__ H,
                                const int* __restrict__ offs, const int* __restrict__ esrc,
                                unsigned short* __restrict__ Hbar, int N) {
    int wave = threadIdx.x >> 6, lane = threadIdx.x & 63;
    int i = vb * 4 + wave;
    if (i >= N) return;
    int half = lane >> 5;
    int c = (lane & 31) * 8;
    float a[8];
#pragma unroll
    for (int j = 0; j < 8; ++j) a[j] = 0.f;
    int e0 = offs[i], e1 = offs[i + 1];
    int e = e0;
    for (; e + 8 <= e1; e += 8) {
        int p0 = esrc[e],     p1 = esrc[e + 1];
        int p2 = esrc[e + 2], p3 = esrc[e + 3];
        int p4 = esrc[e + 4], p5 = esrc[e + 5];
        int p6 = esrc[e + 6], p7 = esrc[e + 7];
        int s0 = half ? p1 : p0;
        int s1 = half ? p3 : p2;
        int s2 = half ? p5 : p4;
        int s3 = half ? p7 : p6;
        ushort8v r0 = *(const ushort8v*)(H + (long)s0 * 1024 + c);
        ushort8v r1 = *(const ushort8v*)(H + (long)s1 * 1024 + c);
        ushort8v r2 = *(const ushort8v*)(H + (long)s2 * 1024 + c);
        ushort8v r3 = *(const ushort8v*)(H + (long)s3 * 1024 + c);
#pragma unroll
        for (int j = 0; j < 8; ++j)
            a[j] += (bf2f(r0[j]) + bf2f(r1[j])) + (bf2f(r2[j]) + bf2f(r3[j]));
    }
    for (; e + 4 <= e1; e += 4) {
        int p0 = esrc[e],     p1 = esrc[e + 1];
        int p2 = esrc[e + 2], p3 = esrc[e + 3];
        int s0 = half ? p1 : p0;
        int s1 = half ? p3 : p2;
        ushort8v r0 = *(const ushort8v*)(H + (long)s0 * 1024 + c);
        ushort8v r1 = *(const ushort8v*)(H + (long)s1 * 1024 + c);
#pragma unroll
        for (int j = 0; j < 8; ++j)
            a[j] += bf2f(r0[j]) + bf2f(r1[j]);
    }
    for (; e < e1; e += 2) {
        int pa = esrc[e];
        int pb = (e + 1 < e1) ? esrc[e + 1] : pa;
        int s = half ? pb : pa;
        float m = (half && (e + 1 >= e1)) ? 0.f : 1.f;
        ushort8v r = *(const ushort8v*)(H + (long)s * 1024 + c);
#pragma unroll
        for (int j = 0; j < 8; ++j)
            a[j] = fmaf(bf2f(r[j]), m, a[j]);
    }
    int d = e1 - e0;
    float inv = (d > 0) ? 1.0f / (float)d : 0.0f;
    ushort8v w;
#pragma unroll
    for (int j = 0; j < 8; ++j) {
        float tsum = a[j] + __shfl_xor(a[j], 32);
        w[j] = f2bf(tsum * inv);
    }
    if (half == 0)
        *(ushort8v*)(Hbar + (long)i * 256 + c) = w;
}

// ---------------- mega kernel ----------------
__global__ __launch_bounds__(256, 6)
void mega_kernel(const float* __restrict__ x,
                 const int* __restrict__ src, const int* __restrict__ dst, int E,
                 const float* __restrict__ W0, const float* __restrict__ W1,
                 const float* __restrict__ W2, const float* __restrict__ Wf,
                 const float* __restrict__ b0p, const float* __restrict__ b1p,
                 const float* __restrict__ b2p, const float* __restrict__ bfp,
                 int* __restrict__ deg, int* __restrict__ offs, int* __restrict__ cursor,
                 int* __restrict__ esrc,
                 unsigned short* __restrict__ Wc0, unsigned short* __restrict__ Wc1,
                 unsigned short* __restrict__ Wc2, unsigned short* __restrict__ Wft,
                 unsigned short* __restrict__ Ucat, unsigned short* __restrict__ Hbar,
                 float* __restrict__ out, int* __restrict__ barr,
                 int N, int EB, int xblocks, int nbScan) {
    __shared__ __align__(16) unsigned char smem[SMEM_BYTES];
    int bid = blockIdx.x, t = threadIdx.x;
    int NB = gridDim.x;
    int xcd = get_xcd();
    int* nxcd = barr + 128;

    // start election: count distinct XCDs hosting blocks (final before any barrier completes)
    if (t == 0) {
        int first = __hip_atomic_fetch_add(barr + xcd * 16, 1, __ATOMIC_RELAXED,
                                           __HIP_MEMORY_SCOPE_AGENT);
        if (first == 0)
            __hip_atomic_fetch_add(nxcd, 1, __ATOMIC_RELAXED, __HIP_MEMORY_SCOPE_AGENT);
    }

    // ================= P0: deg count + W-prep + x->bf16 =================
    {
        float(*ta)[33] = (float(*)[33])smem;
        float(*tb)[33] = (float(*)[33])(smem + 32 * 33 * 4);
        int vbTot = EB + 448 + xblocks;
        for (int bb = bid; bb < vbTot; bb += NB) {
            if (bb < EB) {
                int idx = bb * 256 + t;
                if (idx < E) atomicAdd(&deg[dst[idx]], 1);
            } else {
                int bb2 = bb - EB;
                int r0 = t >> 5, c = t & 31;
                if (bb2 < 192) {
                    const float* W = (bb2 < 64) ? W0 : (bb2 < 128) ? W1 : W2;
                    unsigned short* Wc = (bb2 < 64) ? Wc0 : (bb2 < 128) ? Wc1 : Wc2;
                    int t64 = bb2 & 63;
                    int k0 = (t64 >> 3) * 32, n0 = (t64 & 7) * 32;
#pragma unroll
                    for (int it = 0; it < 4; ++it) {
                        int r = r0 + it * 8;
                        float a = W[(k0 + r) * 256 + n0 + c];
                        float bv = W[(k0 + r + 256) * 256 + n0 + c];
                        ta[r][c] = a - bv;
                        tb[r][c] = bv;
                    }
                    __syncthreads();
#pragma unroll
                    for (int it = 0; it < 4; ++it) {
                        int r = r0 + it * 8;
                        Wc[(n0 + r) * 512 + k0 + c] = f2bf(ta[c][r]);
                        Wc[(n0 + r) * 512 + 256 + k0 + c] = f2bf(tb[c][r]);
                    }
                    __syncthreads();  // LDS reuse across grid-stride iters
                } else if (bb2 < 448) {
                    int t256 = bb2 - 192;
                    int k0 = (t256 >> 3) * 32, n0 = (t256 & 7) * 32;
#pragma unroll
                    for (int it = 0; it < 4; ++it) {
                        int r = r0 + it * 8;
                        ta[r][c] = Wf[(k0 + r) * 256 + n0 + c];
                    }
                    __syncthreads();
#pragma unroll
                    for (int it = 0; it < 4; ++it) {
                        int r = r0 + it * 8;
                        Wft[(n0 + r) * 1024 + k0 + c] = f2bf(ta[c][r]);
                    }
                    __syncthreads();  // LDS reuse across grid-stride iters
                } else {
                    long base = (long)(bb2 - 448) * 2048 + t * 8;
                    if (base < (long)N * 256) {
                        int i = (int)(base >> 8), cc = (int)(base & 255);
                        const float4* xp = (const float4*)(x + base);
                        float4 v0 = xp[0], v1 = xp[1];
                        ushort4 w0, w1;
                        w0.x = f2bf(v0.x); w0.y = f2bf(v0.y); w0.z = f2bf(v0.z); w0.w = f2bf(v0.w);
                        w1.x = f2bf(v1.x); w1.y = f2bf(v1.y); w1.z = f2bf(v1.z); w1.w = f2bf(v1.w);
                        unsigned short* up = Ucat + (long)i * 1024 + cc;
                        *(ushort4*)up = w0;
                        *(ushort4*)(up + 4) = w1;
                    }
                }
            }
        }
    }
    gbar(barr, 0, NB, xcd, nxcd);

    // ================= P1: CSR scan (redundant-prefix), blocks [0,nbScan) =================
    if (bid < nbScan) {
        int* part = (int*)smem;          // [256]
        int* pre = (int*)smem + 256;     // [128]
        int b = bid;
        int beg = b * 128;
        int end = beg + 128; if (end > N) end = N;
        int s = 0;
        for (int i = t; i < beg; i += 256) s += deg[i];
        part[t] = s;
        __syncthreads();
#pragma unroll
        for (int off = 128; off > 0; off >>= 1) {
            if (t < off) part[t] += part[t + off];
            __syncthreads();
        }
        int base = part[0];
        int cnt = end - beg;
        if (t < 128) pre[t] = (t < cnt) ? deg[beg + t] : 0;
        __syncthreads();
        for (int off = 1; off < 128; off <<= 1) {
            int v = 0;
            if (t < 128 && t >= off) v = pre[t - off];
            __syncthreads();
            if (t < 128 && t >= off) pre[t] += v;
            __syncthreads();
        }
        if (t < cnt) {
            int excl = base + (t ? pre[t - 1] : 0);
            offs[beg + t] = excl;
            cursor[beg + t] = excl;
        }
        if (end == N && t == 0) offs[N] = base + (cnt ? pre[cnt - 1] : 0);
    }
    gbar(barr, 1, NB, xcd, nxcd);

    // ================= P2: bucket fill =================
    for (int idx = bid * 256 + t; idx < E; idx += NB * 256) {
        int p = atomicAdd(&cursor[dst[idx]], 1);
        esrc[p] = src[idx];
    }
    gbar(barr, 2, NB, xcd, nxcd);

    // ================= layers =================
    int gm = (N + 63) / 64;
    int ab = (N + 3) / 4;
    int tiles = gm * 4;
#pragma unroll 1
    for (int l = 0; l < 3; ++l) {
        const unsigned short* A1 = Ucat + l * 256;
        const unsigned short* Wc = (l == 0) ? Wc0 : (l == 1) ? Wc1 : Wc2;
        const float* bias = (l == 0) ? b0p : (l == 1) ? b1p : b2p;
        unsigned short* outB = Ucat + (l + 1) * 256;
        unsigned short* Hb = Hbar + (long)l * ((long)N * 256);  // triple buffer: no rewrite

        for (int vb = bid; vb < ab; vb += NB)
            agg_body(vb, A1, offs, esrc, Hb, N);
        gbar(barr, 3 + 2 * l, NB, xcd, nxcd);

        for (int vb = bid; vb < tiles; vb += NB) {
            int bm = vb % gm, bn = vb / gm;
            gemm_body<0, 512>(bm, bn, A1, Hb, Wc, bias, deg, outB, nullptr, N, smem);
        }
        gbar(barr, 4 + 2 * l, NB, xcd, nxcd);
    }

    // ================= final linear =================
    for (int vb = bid; vb < tiles; vb += NB) {
        int bm = vb % gm, bn = vb / gm;
        gemm_body<1, 1024>(bm, bn, Ucat, nullptr, Wft, bfp, nullptr, nullptr, out, N, smem);
    }
}

extern "C" void kernel_launch(void* const* d_in, const int* in_sizes, int n_in,
                              void* d_out, int out_size, void* d_ws, size_t ws_size,
                              hipStream_t stream) {
    const float* x = (const float*)d_in[0];
    const int* ei = (const int*)d_in[1];
    const float* W[3] = {(const float*)d_in[2], (const float*)d_in[4], (const float*)d_in[6]};
    const float* b[3] = {(const float*)d_in[3], (const float*)d_in[5], (const float*)d_in[7]};
    const float* Wfp = (const float*)d_in[8];
    const float* bfp = (const float*)d_in[9];

    int N = in_sizes[0] / 256;
    int E = in_sizes[1] / 2;
    const int* src = ei;
    const int* dst = ei + E;

    char* p = (char*)d_ws;
    auto alloc = [&](size_t bytes) { char* r = p; p += (bytes + 255) & ~(size_t)255; return r; };
    size_t degPad = ((size_t)N * 4 + 255) & ~(size_t)255;
    int* deg = (int*)alloc(degPad);
    int* barr = (int*)alloc(16384);               // contiguous after deg (both zeroed below)
    int* offs = (int*)alloc((size_t)(N + 1) * 4);
    int* cursor = (int*)alloc((size_t)N * 4);
    int* esrc = (int*)alloc((size_t)E * 4);
    unsigned short* Wc[3];
    for (int l = 0; l < 3; l++) Wc[l] = (unsigned short*)alloc(256 * 512 * 2);
    unsigned short* Wft = (unsigned short*)alloc(256 * 1024 * 2);
    unsigned short* Ucat = (unsigned short*)alloc((size_t)N * 1024 * 2);
    unsigned short* Hbar = (unsigned short*)alloc((size_t)3 * N * 256 * 2);  // triple

    hipMemsetAsync(deg, 0, degPad + 16384, stream);  // zero deg + barrier region

    int EB = (E + 255) / 256;
    int xblocks = (N * 256 + 2047) / 2048;
    int nbScan = (N + 127) / 128;
    int NB = 1536;  // 6 blocks/CU co-resident under launch_bounds(256,6)+18KB LDS

    mega_kernel<<<NB, 256, 0, stream>>>(x, src, dst, E,
                                        W[0], W[1], W[2], Wfp,
                                        b[0], b[1], b[2], bfp,
                                        deg, offs, cursor, esrc,
                                        Wc[0], Wc[1], Wc[2], Wft,
                                        Ucat, Hbar, (float*)d_out, barr,
                                        N, EB, xblocks, nbScan);
}